// Round 3
// baseline (34.709 us; speedup 1.0000x reference)
//
#include <hip/hip_runtime.h>

#define BATCH 384
#define DIM   1024
#define MARGIN_F 0.5f
#define EPS_F 1e-16f
#define N2 (BATCH * BATCH)

// ---------------------------------------------------------------------------
// Kernel 1: split-K partial gram matrix (dot products), 32x32 tile / block.
// dot_z[i][j] = sum_{k in slice z} E[i][k]*E[j][k]   (1 fma per output*k)
// Strided 2x2 micro-tile: thread (tx,ty) owns rows {ty,ty+16} x cols {tx,tx+16}.
// LDS read as float4 (ds_read_b128); row pad 36 floats keeps 16B alignment
// and <=2-way bank aliasing (free). Diagonal blocks also write dot_ii partials
// to ddiag so the consumer can form d^2 = diag_i + diag_j - 2*dot_ij with an
// EXACT 0.0 on the diagonal (identical values summed in identical order).
// Block (0,0,0) also zeroes the finalize counter (runs before triplet_kernel).
// ---------------------------------------------------------------------------
__global__ __launch_bounds__(256) void dist_kernel(const float* __restrict__ E,
                                                   float* __restrict__ dpart,
                                                   float* __restrict__ ddiag,
                                                   int* __restrict__ counter,
                                                   int kslice) {
    __shared__ float As[32][36];
    __shared__ float Bs[32][36];

    if (blockIdx.x == 0 && blockIdx.y == 0 && blockIdx.z == 0 && threadIdx.x == 0)
        *counter = 0;

    const int tx = threadIdx.x & 15;
    const int ty = threadIdx.x >> 4;
    const int rb = blockIdx.y * 32;
    const int cb = blockIdx.x * 32;
    const int kb = blockIdx.z * kslice;

    float acc00 = 0.f, acc01 = 0.f, acc10 = 0.f, acc11 = 0.f;

    const int lr = threadIdx.x >> 3;        // 0..31 row within tile
    const int lc = (threadIdx.x & 7) * 4;   // 0,4,...,28

    for (int k0 = 0; k0 < kslice; k0 += 32) {
        float4 av = *(const float4*)&E[(size_t)(rb + lr) * DIM + kb + k0 + lc];
        float4 bv = *(const float4*)&E[(size_t)(cb + lr) * DIM + kb + k0 + lc];
        *(float4*)&As[lr][lc] = av;
        *(float4*)&Bs[lr][lc] = bv;
        __syncthreads();

#pragma unroll
        for (int k = 0; k < 32; k += 4) {
            float4 a0 = *(const float4*)&As[ty][k];
            float4 a1 = *(const float4*)&As[ty + 16][k];
            float4 b0 = *(const float4*)&Bs[tx][k];
            float4 b1 = *(const float4*)&Bs[tx + 16][k];
            acc00 += a0.x * b0.x + a0.y * b0.y + a0.z * b0.z + a0.w * b0.w;
            acc01 += a0.x * b1.x + a0.y * b1.y + a0.z * b1.z + a0.w * b1.w;
            acc10 += a1.x * b0.x + a1.y * b0.y + a1.z * b0.z + a1.w * b0.w;
            acc11 += a1.x * b1.x + a1.y * b1.y + a1.z * b1.z + a1.w * b1.w;
        }
        __syncthreads();
    }

    float* dst = dpart + (size_t)blockIdx.z * N2;
    const int r0 = rb + ty, r1 = rb + ty + 16;
    const int c0 = cb + tx, c1 = cb + tx + 16;
    dst[(size_t)r0 * BATCH + c0] = acc00;
    dst[(size_t)r0 * BATCH + c1] = acc01;
    dst[(size_t)r1 * BATCH + c0] = acc10;
    dst[(size_t)r1 * BATCH + c1] = acc11;

    if (blockIdx.x == blockIdx.y && tx == ty) {
        ddiag[blockIdx.z * BATCH + r0] = acc00;   // == dot_z[r0][r0]
        ddiag[blockIdx.z * BATCH + r1] = acc11;   // == dot_z[r1][r1]
    }
}

// ---------------------------------------------------------------------------
// Kernel 2: per-anchor triplet reduction + fused last-block finalize.
// ---------------------------------------------------------------------------
__global__ __launch_bounds__(256) void triplet_kernel(const float* __restrict__ dpart,
                                                      const float* __restrict__ ddiag,
                                                      const int* __restrict__ labels,
                                                      float* __restrict__ part,
                                                      int* __restrict__ counter,
                                                      float* __restrict__ out,
                                                      int nslice) {
    __shared__ float drow[BATCH];
    __shared__ int   lab[BATCH];
    __shared__ int   plist[BATCH];
    __shared__ int   npos_s;
    __shared__ float ssum[4];
    __shared__ int   spos[4];
    __shared__ int   sval[4];
    __shared__ int   lastFlag;
    __shared__ double red[12];

    const int t = threadIdx.x;
    const int a = blockIdx.x;

    float da = 0.f;
    for (int z = 0; z < nslice; ++z) da += ddiag[z * BATCH + a];

    for (int i = t; i < BATCH; i += 256) {
        float row = 0.f, di = 0.f;
        for (int z = 0; z < nslice; ++z) {
            row += dpart[(size_t)z * N2 + (size_t)a * BATCH + i];
            di  += ddiag[z * BATCH + i];
        }
        const float s = da + di - 2.f * row;   // exactly 0.0 at i==a
        drow[i] = s > 0.f ? sqrtf(s) : 0.f;
        lab[i]  = labels[i];
    }
    __syncthreads();

    const int la = lab[a];

    // deterministic positives-list build on wave 0
    if (t < 64) {
        int cnt = 0;
#pragma unroll
        for (int c = 0; c < BATCH; c += 64) {
            const int i = c + t;
            const bool f = (lab[i] == la) && (i != a);
            const unsigned long long m = __ballot(f);
            if (f) {
                const int off = __popcll(m & ((1ull << t) - 1ull));
                plist[cnt + off] = i;
            }
            cnt += __popcll(m);
        }
        if (t == 0) npos_s = cnt;
    }
    __syncthreads();

    const int npos = npos_s;
    float sum = 0.f;
    int   pos = 0, valid = 0;

    for (int n = t; n < BATCH; n += 256) {
        if (lab[n] != la) {
            const float dan = drow[n];
            valid += npos;
            for (int q = 0; q < npos; ++q) {
                float tl = drow[plist[q]] - dan + MARGIN_F;
                if (tl > EPS_F) { sum += tl; ++pos; }
            }
        }
    }

#pragma unroll
    for (int off = 32; off > 0; off >>= 1) {
        sum   += __shfl_down(sum, off);
        pos   += __shfl_down(pos, off);
        valid += __shfl_down(valid, off);
    }
    const int wave = t >> 6, lane = t & 63;
    if (lane == 0) { ssum[wave] = sum; spos[wave] = pos; sval[wave] = valid; }
    __syncthreads();

    if (t == 0) {
        float s = 0.f; int p2 = 0, v = 0;
#pragma unroll
        for (int w = 0; w < 4; ++w) { s += ssum[w]; p2 += spos[w]; v += sval[w]; }
        part[a]             = s;
        part[BATCH + a]     = (float)p2;
        part[2 * BATCH + a] = (float)v;
        __threadfence();                       // release partials
        const int old = atomicAdd(counter, 1); // device-scope
        lastFlag = (old == BATCH - 1);
    }
    __syncthreads();

    if (lastFlag) {
        __threadfence();                       // acquire all partials
        double s = 0.0, p = 0.0, v = 0.0;
        for (int i = t; i < BATCH; i += 256) {
            s += (double)part[i];
            p += (double)part[BATCH + i];
            v += (double)part[2 * BATCH + i];
        }
#pragma unroll
        for (int off = 32; off > 0; off >>= 1) {
            s += __shfl_down(s, off);
            p += __shfl_down(p, off);
            v += __shfl_down(v, off);
        }
        if (lane == 0) { red[wave] = s; red[4 + wave] = p; red[8 + wave] = v; }
        __syncthreads();
        if (t == 0) {
            double fs = 0.0, fp = 0.0, fv = 0.0;
#pragma unroll
            for (int w = 0; w < 4; ++w) { fs += red[w]; fp += red[4 + w]; fv += red[8 + w]; }
            out[0] = (float)(fs / (fp + 1e-16));
            out[1] = (float)fp;
            out[2] = (float)fv;
        }
    }
}

extern "C" void kernel_launch(void* const* d_in, const int* in_sizes, int n_in,
                              void* d_out, int out_size, void* d_ws, size_t ws_size,
                              hipStream_t stream) {
    const int*   labels = (const int*)d_in[0];
    const float* E      = (const float*)d_in[1];
    float* out = (float*)d_out;

    // ws layout: [counter @0][part @256: 3*384 f][ddiag @8192: S*384 f][dpart @24576]
    int*   counter = (int*)d_ws;
    float* part    = (float*)((char*)d_ws + 256);
    float* ddiag   = (float*)((char*)d_ws + 8192);
    float* dpart   = (float*)((char*)d_ws + 24576);

    int S = 8;
    while (S > 1 && 24576 + (size_t)S * N2 * sizeof(float) > ws_size) S >>= 1;
    const int kslice = DIM / S;

    dim3 grid(BATCH / 32, BATCH / 32, S);
    dist_kernel<<<grid, 256, 0, stream>>>(E, dpart, ddiag, counter, kslice);
    triplet_kernel<<<BATCH, 256, 0, stream>>>(dpart, ddiag, labels, part, counter, out, S);
}